// Round 9
// baseline (8720.845 us; speedup 1.0000x reference)
//
#include <hip/hip_runtime.h>
#include <math.h>

// ---------------- problem constants ----------------
#define NEDU  1024
#define LTOK  20
#define CW    330     // 300 word + 30 pos
#define HDIM  256
#define FEAT  930
#define MSLOT 1026    // N_EDUS + 2
#define NWG   128     // parse workgroups (1 wave each); WG bx owns h-indices 2bx, 2bx+1

typedef unsigned long long u64;

// ---------------- workspace layout (32-bit word offsets) ----------------
#define O_WCATT 0
#define SZ_WCATT (330*600)
#define O_F     (O_WCATT + SZ_WCATT)
#define SZ_F    (NEDU*FEAT)
#define O_BUFH  (O_F + SZ_F)
#define SZ_BUF  (MSLOT*HDIM)
#define O_BUFC  (O_BUFH + SZ_BUF)
#define O_STKT  (O_BUFC + SZ_BUF)          // tagged stack_h [slot][j] u32
#define O_THT   (O_STKT + MSLOT*HDIM)      // tagged tracker h, 2 parities
#define O_RHT   (O_THT + 2*HDIM)           // tagged compose rh
#define O_LOSSP (O_RHT + HDIM)             // loss partials [2048][256] float
#define NZERO   ((MSLOT + 3) * HDIM)       // stkT + thT(2) + rhT -> zeros w/ tag 0

#define AG __HIP_MEMORY_SCOPE_AGENT
__device__ __forceinline__ u64 aload64(const u64* p) {
  return __hip_atomic_load(p, __ATOMIC_RELAXED, AG);
}
__device__ __forceinline__ void astore64(u64* p, u64 v) {
  __hip_atomic_store(p, v, __ATOMIC_RELAXED, AG);
}
__device__ __forceinline__ unsigned tagbits(float v, unsigned ver) {
  return (__float_as_uint(v) & ~3u) | (ver & 3u);
}
__device__ __forceinline__ bool tagok(u64 v, unsigned tag) {
  return (((unsigned)v & 3u) == tag) & (((unsigned)(v >> 32) & 3u) == tag);
}
__device__ __forceinline__ float sigm(float x) { return 1.f / (1.f + expf(-x)); }
__device__ __forceinline__ void unpack(u64 a, u64 b, float* x) {
  x[0] = __uint_as_float((unsigned)a); x[1] = __uint_as_float((unsigned)(a >> 32));
  x[2] = __uint_as_float((unsigned)b); x[3] = __uint_as_float((unsigned)(b >> 32));
}
// spin-gather one tagged 256-vector: lane gets elements 4l..4l+3
__device__ __forceinline__ void gather1T(const unsigned* base, int lane, unsigned tag,
                                         float* x) {
  const u64* p = (const u64*)base + 2 * lane;
  for (int it = 0;; ++it) {
    const u64 a = aload64(p), b = aload64(p + 1);
    if (__ballot(tagok(a, tag) & tagok(b, tag)) == ~0ull) { unpack(a, b, x); return; }
    if (it > 48) __builtin_amdgcn_s_sleep(1);
  }
}
// combined retry for two tagged vectors
__device__ __forceinline__ void gather2T(const unsigned* b1, unsigned t1,
                                         const unsigned* b2, unsigned t2,
                                         int lane, float* x1, float* x2) {
  const u64* p1 = (const u64*)b1 + 2 * lane;
  const u64* p2 = (const u64*)b2 + 2 * lane;
  for (int it = 0;; ++it) {
    const u64 a = aload64(p1), b = aload64(p1 + 1);
    const u64 c = aload64(p2), d = aload64(p2 + 1);
    const bool ok = tagok(a, t1) & tagok(b, t1) & tagok(c, t2) & tagok(d, t2);
    if (__ballot(ok) == ~0ull) { unpack(a, b, x1); unpack(c, d, x2); return; }
    if (it > 48) __builtin_amdgcn_s_sleep(1);
  }
}

// ---------------- prep: weight transpose + zeroing ----------------
__global__ void prep_kernel(const float* __restrict__ Wu, const float* __restrict__ Wb,
                            const float* __restrict__ Wt, float* __restrict__ ws) {
  const int i0 = blockIdx.x * blockDim.x + threadIdx.x;
  const int st = gridDim.x * blockDim.x;
  for (int i = i0; i < SZ_WCATT; i += st) {
    const int k = i / 600, c = i - 600 * k;
    float v;
    if (c < 100)      v = Wu[c * 330 + k];
    else if (c < 300) { const int q = c - 100; v = Wb[(q % 100) * 660 + (q / 100) * 330 + k]; }
    else              { const int q = c - 300; v = Wt[(q % 100) * 990 + (q / 100) * 330 + k]; }
    ws[O_WCATT + i] = v;
  }
  unsigned* z = (unsigned*)ws + O_STKT;
  for (int i = i0; i < NZERO; i += st) z[i] = 0u;              // zeros with ver-0 tags
  for (int i = i0; i < 2 * HDIM; i += st) {                    // buf zero rows 1024,1025
    ws[O_BUFH + NEDU * HDIM + i] = 0.f;
    ws[O_BUFC + NEDU * HDIM + i] = 0.f;
  }
}

// ---------------- encode (unchanged) ----------------
__global__ __launch_bounds__(256) void encode_kernel(
    const int* __restrict__ edu_words, const int* __restrict__ edu_poses,
    const float* __restrict__ word_emb, const float* __restrict__ pos_emb,
    const float* __restrict__ bu, const float* __restrict__ bb,
    const float* __restrict__ bt, float* __restrict__ ws) {
  __shared__ __align__(16) float xlT[CW * LTOK];
  __shared__ float zl[300 * 21];
  __shared__ float convout[300];
  const int n = blockIdx.x, tid = threadIdx.x;
  const float* WcatT = ws + O_WCATT;

  for (int i = tid; i < LTOK * CW; i += 256) {
    const int l = i / CW, k = i - l * CW;
    float v;
    if (k < 300) v = word_emb[(size_t)edu_words[n * LTOK + l] * 300 + k];
    else         v = pos_emb[(size_t)edu_poses[n * LTOK + l] * 30 + (k - 300)];
    xlT[k * LTOK + l] = v;
  }
  __syncthreads();

  for (int f = tid; f < 300; f += 256) {
    float acc[LTOK];
#pragma unroll
    for (int l = 0; l < LTOK; ++l) acc[l] = 0.f;
    for (int k = 0; k < CW; ++k) {
      const float w = WcatT[k * 600 + f];
      const float4* xp = (const float4*)(xlT + k * LTOK);
      union { float4 v[5]; float s[20]; } xu;
      xu.v[0] = xp[0]; xu.v[1] = xp[1]; xu.v[2] = xp[2]; xu.v[3] = xp[3]; xu.v[4] = xp[4];
#pragma unroll
      for (int l = 0; l < LTOK; ++l) acc[l] += w * xu.s[l];
    }
#pragma unroll
    for (int l = 0; l < LTOK; ++l) zl[f * 21 + l] = acc[l];
  }
  __syncthreads();
  if (tid < 200) {
    float m;
    if (tid < 100) {
      const int f = tid; const float b = bu[f];
      m = zl[f * 21] + b;
      for (int l = 1; l < 20; ++l) m = fmaxf(m, zl[f * 21 + l] + b);
    } else {
      const int f = tid - 100; const float b = bb[f];
      const float* z0 = zl + (100 + f) * 21;
      const float* z1 = zl + (200 + f) * 21;
      m = z1[0] + b;
      for (int u = 1; u <= 19; ++u) m = fmaxf(m, z0[u - 1] + z1[u] + b);
      m = fmaxf(m, z0[19] + b);
    }
    convout[tid] = fmaxf(m, 0.f);
  }
  __syncthreads();

  for (int f = tid; f < 300; f += 256) {
    float acc[LTOK];
#pragma unroll
    for (int l = 0; l < LTOK; ++l) acc[l] = 0.f;
    for (int k = 0; k < CW; ++k) {
      const float w = WcatT[k * 600 + 300 + f];
      const float4* xp = (const float4*)(xlT + k * LTOK);
      union { float4 v[5]; float s[20]; } xu;
      xu.v[0] = xp[0]; xu.v[1] = xp[1]; xu.v[2] = xp[2]; xu.v[3] = xp[3]; xu.v[4] = xp[4];
#pragma unroll
      for (int l = 0; l < LTOK; ++l) acc[l] += w * xu.s[l];
    }
#pragma unroll
    for (int l = 0; l < LTOK; ++l) zl[f * 21 + l] = acc[l];
  }
  __syncthreads();
  if (tid < 100) {
    const int f = tid; const float b = bt[f];
    const float* z0 = zl + f * 21;
    const float* z1 = zl + (100 + f) * 21;
    const float* z2 = zl + (200 + f) * 21;
    float m = z2[0] + b;
    m = fmaxf(m, z1[0] + z2[1] + b);
    for (int u = 2; u <= 19; ++u) m = fmaxf(m, z0[u - 2] + z1[u - 1] + z2[u] + b);
    m = fmaxf(m, z0[18] + z1[19] + b);
    m = fmaxf(m, z0[19] + b);
    convout[200 + f] = fmaxf(m, 0.f);
  }
  __syncthreads();

  float* Fr = ws + O_F + (size_t)n * FEAT;
  for (int j = tid; j < FEAT; j += 256) {
    float v;
    if (j < 300)      v = xlT[j * LTOK + 0];
    else if (j < 600) v = xlT[(j - 300) * LTOK + 19];
    else if (j < 630) v = xlT[(j - 300) * LTOK + 0];
    else              v = convout[j - 630];
    Fr[j] = v;
  }
}

// ---------------- proj (unchanged) ----------------
__global__ __launch_bounds__(256) void proj_kernel(const float* __restrict__ Wp,
                                                   const float* __restrict__ bp,
                                                   float* __restrict__ ws) {
  __shared__ float As[64][17];
  __shared__ float Bs[64][17];
  const float* F = ws + O_F;
  float* bufh = ws + O_BUFH;
  float* bufc = ws + O_BUFC;
  const int tid = threadIdx.x;
  const int m0 = blockIdx.x * 64, n0 = blockIdx.y * 64;
  const int mm0 = (tid & 15) * 4, nn0 = (tid >> 4) * 4;
  float acc[4][4] = {{0.f}};
  for (int k0 = 0; k0 < FEAT; k0 += 16) {
    for (int i = tid; i < 64 * 16; i += 256) {
      const int mm = i >> 4, kk = i & 15;
      const int gk = k0 + kk;
      As[mm][kk] = (gk < FEAT) ? F[(size_t)(m0 + mm) * FEAT + gk] : 0.f;
      Bs[mm][kk] = (gk < FEAT) ? Wp[(size_t)(n0 + mm) * FEAT + gk] : 0.f;
    }
    __syncthreads();
#pragma unroll
    for (int kk = 0; kk < 16; ++kk) {
      float av[4], bv[4];
#pragma unroll
      for (int i = 0; i < 4; ++i) av[i] = As[mm0 + i][kk];
#pragma unroll
      for (int j = 0; j < 4; ++j) bv[j] = Bs[nn0 + j][kk];
#pragma unroll
      for (int i = 0; i < 4; ++i)
#pragma unroll
        for (int j = 0; j < 4; ++j) acc[i][j] += av[i] * bv[j];
    }
    __syncthreads();
  }
#pragma unroll
  for (int i = 0; i < 4; ++i) {
    const int m = m0 + mm0 + i;
#pragma unroll
    for (int j = 0; j < 4; ++j) {
      const int nn = n0 + nn0 + j;
      const float v = acc[i][j] + bp[nn];
      if (nn < 256) bufh[(size_t)m * 256 + nn] = v;
      else          bufc[(size_t)m * 256 + (nn - 256)] = v;
    }
  }
}

// ---------------- parse: 128 x single-wave WGs, barrier-free, R4 protocol ----------------
__global__ __launch_bounds__(64, 1) void parse_kernel(
    const int* __restrict__ transes, int nT,
    const float* __restrict__ Wih, const float* __restrict__ Whh,
    const float* __restrict__ bih, const float* __restrict__ bhh,
    const float* __restrict__ Wc, const float* __restrict__ bc,
    const float* __restrict__ Wsc, float* __restrict__ ws) {
  const int lane = threadIdx.x;        // 0..63, one wave per WG
  const int bx = blockIdx.x;
  const int j0 = bx * 2;               // owned h-indices j0, j0+1

  const float* bufh = ws + O_BUFH;
  const float* bufc = ws + O_BUFC;
  unsigned* stkT = (unsigned*)ws + O_STKT;
  unsigned* thT  = (unsigned*)ws + O_THT;
  unsigned* rhT  = (unsigned*)ws + O_RHT;
  float* lossp   = ws + O_LOSSP;

  __shared__ float sc_lds[MSLOT][2];   // stack-c for owned j's (lane0, wave-sync)
  __shared__ unsigned vstk[MSLOT];     // slot version table (lane0 writes, wave-sync)

  // ---- track rows q = gate*2 + jj (8 rows); element e = 4*lane + c ----
  float wt[8][16]; float bt_[8];
#pragma unroll
  for (int q = 0; q < 8; ++q) {
    const int rg = (q >> 1) * 256 + j0 + (q & 1);
#pragma unroll
    for (int blk = 0; blk < 3; ++blk) {
      const float4 w = *(const float4*)(Wih + (size_t)rg * 768 + blk * 256 + 4 * lane);
      wt[q][4 * blk + 0] = w.x; wt[q][4 * blk + 1] = w.y;
      wt[q][4 * blk + 2] = w.z; wt[q][4 * blk + 3] = w.w;
    }
    const float4 wh = *(const float4*)(Whh + (size_t)rg * 256 + 4 * lane);
    wt[q][12] = wh.x; wt[q][13] = wh.y; wt[q][14] = wh.z; wt[q][15] = wh.w;
    bt_[q] = bih[rg] + bhh[rg];
  }
  // ---- compose rows q = gate*2 + jj (10 rows: gates a,i,f1,f2,o) ----
  float wcm[10][12]; float bc_[10];
#pragma unroll
  for (int q = 0; q < 10; ++q) {
    const int rg = (q >> 1) * 256 + j0 + (q & 1);
#pragma unroll
    for (int blk = 0; blk < 3; ++blk) {
      const float4 w = *(const float4*)(Wc + (size_t)rg * 768 + blk * 256 + 4 * lane);
      wcm[q][4 * blk + 0] = w.x; wcm[q][4 * blk + 1] = w.y;
      wcm[q][4 * blk + 2] = w.z; wcm[q][4 * blk + 3] = w.w;
    }
    bc_[q] = bc[rg];
  }
  const float ws00 = Wsc[j0], ws01 = Wsc[j0 + 1];
  const float ws10 = Wsc[256 + j0], ws11 = Wsc[256 + j0 + 1];

  for (int i = lane; i < MSLOT; i += 64) vstk[i] = 0u;
  if (lane == 0) { sc_lds[0][0] = sc_lds[0][1] = 0.f; sc_lds[1][0] = sc_lds[1][1] = 0.f; }
  __syncthreads();   // once, after init

  unsigned V = 0, vrh = 0;
  int sptr = 2, bptr = 0;
  float tc0 = 0.f, tc1 = 0.f;      // tracker c (lane 0)
  float rh0 = 0.f, rh1 = 0.f;      // compose rh (lane 0)
  float xth[4];                    // th(V) per-lane cache (compose -> trackR)

  auto red8 = [&](float* d) {
#pragma unroll
    for (int off = 32; off; off >>= 1) {
#pragma unroll
      for (int q = 0; q < 8; ++q) d[q] += __shfl_down(d[q], off, 64);
    }
  };
  auto red10 = [&](float* d) {
#pragma unroll
    for (int off = 32; off; off >>= 1) {
#pragma unroll
      for (int q = 0; q < 10; ++q) d[q] += __shfl_down(d[q], off, 64);
    }
  };

  // fin (lane 0): gates in d[0..7]+bias -> LSTM update, publish th pair, loss
  auto fin_track = [&](float* d) {
    if (lane == 0) {
      float th_[2];
#pragma unroll
      for (int jj = 0; jj < 2; ++jj) {
        const float gi = d[0 + jj] + bt_[0 + jj];
        const float gf = d[2 + jj] + bt_[2 + jj];
        const float gg = d[4 + jj] + bt_[4 + jj];
        const float go = d[6 + jj] + bt_[6 + jj];
        const float tcp = jj ? tc1 : tc0;
        const float cn = sigm(gf) * tcp + sigm(gi) * tanhf(gg);
        if (jj) tc1 = cn; else tc0 = cn;
        th_[jj] = sigm(go) * tanhf(cn);
      }
      const u64 pack = (u64)tagbits(th_[0], V + 1) | ((u64)tagbits(th_[1], V + 1) << 32);
      astore64((u64*)(thT + ((V + 1) & 1) * HDIM + j0), pack);
      float2 lp;
      lp.x = ws00 * th_[0] + ws01 * th_[1];
      lp.y = ws10 * th_[0] + ws11 * th_[1];
      *(float2*)(lossp + (size_t)V * 256 + bx * 2) = lp;
    }
    V += 1;
  };

  // static track partial: d[q] = blocks 0..2 dot, unreduced
  auto stat3 = [&](const float* p1, const float* p2, const float* p3, float* d) {
#pragma unroll
    for (int q = 0; q < 8; ++q) {
      float a = 0.f;
#pragma unroll
      for (int c = 0; c < 4; ++c)
        a += wt[q][c] * p1[c] + wt[q][4 + c] * p2[c] + wt[q][8 + c] * p3[c];
      d[q] = a;
    }
  };

  // ---- initial track: statics stack[1],stack[0] (v0), bufh[0]; fresh th(v0) ----
  {
    const float4 f3 = *(const float4*)(bufh + 4 * lane);
    float p1[4], p2[4], xf[4];
    gather2T(stkT + HDIM, 0u, stkT, 0u, lane, p1, p2);
    const float p3[4] = { f3.x, f3.y, f3.z, f3.w };
    float d[8];
    stat3(p1, p2, p3, d);
    gather1T(thT, lane, 0u, xf);
#pragma unroll
    for (int q = 0; q < 8; ++q) {
#pragma unroll
      for (int c = 0; c < 4; ++c) d[q] += wt[q][12 + c] * xf[c];
    }
    red8(d);
    fin_track(d);
  }

  for (int t = 0; t < nT; ++t) {
    const int tr = transes[t];
    if (tr) {
      // ==== compose: statics h1,h2; fresh th(V); cache xth for trackR ====
      {
        float h1[4], h2[4];
        gather2T(stkT + (size_t)(sptr - 1) * HDIM, vstk[sptr - 1] & 3,
                 stkT + (size_t)(sptr - 2) * HDIM, vstk[sptr - 2] & 3, lane, h1, h2);
        float e[10];
#pragma unroll
        for (int q = 0; q < 10; ++q) {
          float a = 0.f;
#pragma unroll
          for (int c = 0; c < 4; ++c)
            a += wcm[q][c] * h1[c] + wcm[q][4 + c] * h2[c];
          e[q] = a;
        }
        gather1T(thT + (V & 1) * HDIM, lane, V & 3, xth);
#pragma unroll
        for (int q = 0; q < 10; ++q) {
#pragma unroll
          for (int c = 0; c < 4; ++c) e[q] += wcm[q][8 + c] * xth[c];
        }
        red10(e);
        if (lane == 0) {
          float rhv[2];
#pragma unroll
          for (int jj = 0; jj < 2; ++jj) {
            const float ga = e[0 + jj] + bc_[0 + jj];
            const float gi = e[2 + jj] + bc_[2 + jj];
            const float gf1 = e[4 + jj] + bc_[4 + jj];
            const float gf2 = e[6 + jj] + bc_[6 + jj];
            const float go = e[8 + jj] + bc_[8 + jj];
            const float c1 = sc_lds[sptr - 1][jj];
            const float c2 = sc_lds[sptr - 2][jj];
            const float rc = tanhf(ga) * sigm(gi) + sigm(gf1) * c1 + sigm(gf2) * c2;
            sc_lds[sptr - 2][jj] = rc;
            rhv[jj] = sigm(go) * tanhf(rc);
          }
          rh0 = rhv[0]; rh1 = rhv[1];
          const u64 pack = (u64)tagbits(rh0, vrh + 1) | ((u64)tagbits(rh1, vrh + 1) << 32);
          astore64((u64*)(rhT + j0), pack);
        }
        vrh += 1;
      }
      // ==== trackR: statics stack[sptr-3], bufh[bptr], th cached; fresh rh ====
      {
        const float4 f3 = *(const float4*)(bufh + (size_t)bptr * HDIM + 4 * lane);
        float p2[4];
        gather1T(stkT + (size_t)(sptr - 3) * HDIM, lane, vstk[sptr - 3] & 3, p2);
        const float p3[4] = { f3.x, f3.y, f3.z, f3.w };
        float d[8];
#pragma unroll
        for (int q = 0; q < 8; ++q) {
          float a = 0.f;
#pragma unroll
          for (int c = 0; c < 4; ++c)
            a += wt[q][4 + c] * p2[c] + wt[q][8 + c] * p3[c] + wt[q][12 + c] * xth[c];
          d[q] = a;
        }
        float xr[4];
        gather1T(rhT, lane, vrh & 3, xr);
        // deferred stack write: rh(vrh) fully visible => all WGs' compose reads
        // of slot sptr-2 are complete. Safe to overwrite.
        const unsigned nv2 = vstk[sptr - 2] + 1;
        if (lane == 0) {
          const u64 pack = (u64)tagbits(rh0, nv2) | ((u64)tagbits(rh1, nv2) << 32);
          astore64((u64*)(stkT + (size_t)(sptr - 2) * HDIM + j0), pack);
          vstk[sptr - 2] = nv2;
        }
#pragma unroll
        for (int q = 0; q < 8; ++q) {
#pragma unroll
          for (int c = 0; c < 4; ++c) d[q] += wt[q][c] * xr[c];
        }
        red8(d);
        fin_track(d);
        sptr -= 1;
      }
    } else {
      // ==== trackS: early push; statics bufh[bptr], stack[sptr-1], bufh[bptr+1];
      //      fresh th(V) ====
      const unsigned nv = vstk[sptr] + 1;
      if (lane == 0) {
        const float b0 = bufh[(size_t)bptr * HDIM + j0];
        const float b1 = bufh[(size_t)bptr * HDIM + j0 + 1];
        const u64 pack = (u64)tagbits(b0, nv) | ((u64)tagbits(b1, nv) << 32);
        astore64((u64*)(stkT + (size_t)sptr * HDIM + j0), pack);
        sc_lds[sptr][0] = bufc[(size_t)bptr * HDIM + j0];
        sc_lds[sptr][1] = bufc[(size_t)bptr * HDIM + j0 + 1];
        vstk[sptr] = nv;
      }
      const float4 f1 = *(const float4*)(bufh + (size_t)bptr * HDIM + 4 * lane);
      const float4 f3 = *(const float4*)(bufh + (size_t)(bptr + 1) * HDIM + 4 * lane);
      float p2[4], xf[4];
      gather1T(stkT + (size_t)(sptr - 1) * HDIM, lane, vstk[sptr - 1] & 3, p2);
      const float p1[4] = { f1.x, f1.y, f1.z, f1.w };
      const float p3[4] = { f3.x, f3.y, f3.z, f3.w };
      float d[8];
      stat3(p1, p2, p3, d);
      gather1T(thT + (V & 1) * HDIM, lane, V & 3, xf);
#pragma unroll
      for (int q = 0; q < 8; ++q) {
#pragma unroll
        for (int c = 0; c < 4; ++c) d[q] += wt[q][12 + c] * xf[c];
      }
      red8(d);
      fin_track(d);
      sptr += 1; bptr += 1;
    }
  }
}

// ---------------- loss reduce: partials -> mean NLL ----------------
__global__ __launch_bounds__(256) void loss_kernel(const int* __restrict__ transes, int nT,
                                                   const float* __restrict__ bsc,
                                                   const float* __restrict__ ws,
                                                   float* __restrict__ out) {
  const int tid = threadIdx.x;
  const float* lossp = ws + O_LOSSP;
  __shared__ double red[256];
  double acc = 0.0;
  for (int t = tid; t < nT; t += 256) {
    const float2* lp = (const float2*)(lossp + (size_t)t * 256);
    float a0 = 0.f, a1 = 0.f;
    for (int w = 0; w < NWG; ++w) { const float2 v = lp[w]; a0 += v.x; a1 += v.y; }
    const float l0 = a0 + bsc[0], l1 = a1 + bsc[1];
    const float mx = fmaxf(l0, l1);
    acc += (double)(mx + logf(expf(l0 - mx) + expf(l1 - mx)) - (transes[t] ? l1 : l0));
  }
  red[tid] = acc;
  __syncthreads();
  for (int s = 128; s; s >>= 1) {
    if (tid < s) red[tid] += red[tid + s];
    __syncthreads();
  }
  if (tid == 0) out[0] = (float)(red[0] / (double)nT);
}

// ---------------- launch ----------------
extern "C" void kernel_launch(void* const* d_in, const int* in_sizes, int n_in,
                              void* d_out, int out_size, void* d_ws, size_t ws_size,
                              hipStream_t stream) {
  const int*   edu_words = (const int*)d_in[0];
  const int*   edu_poses = (const int*)d_in[1];
  const int*   transes   = (const int*)d_in[2];
  const float* word_emb  = (const float*)d_in[3];
  const float* pos_emb   = (const float*)d_in[4];
  const float* Wu  = (const float*)d_in[5];
  const float* bu  = (const float*)d_in[6];
  const float* Wb  = (const float*)d_in[7];
  const float* bb  = (const float*)d_in[8];
  const float* Wt  = (const float*)d_in[9];
  const float* bt  = (const float*)d_in[10];
  const float* Wp  = (const float*)d_in[11];
  const float* bp  = (const float*)d_in[12];
  const float* Wih = (const float*)d_in[13];
  const float* Whh = (const float*)d_in[14];
  const float* bih = (const float*)d_in[15];
  const float* bhh = (const float*)d_in[16];
  const float* Wc  = (const float*)d_in[17];
  const float* bc  = (const float*)d_in[18];
  const float* Wsc = (const float*)d_in[19];
  const float* bsc = (const float*)d_in[20];
  float* ws  = (float*)d_ws;
  float* out = (float*)d_out;
  int nT = in_sizes[2];

  hipLaunchKernelGGL(prep_kernel, dim3(256), dim3(256), 0, stream, Wu, Wb, Wt, ws);
  hipLaunchKernelGGL(encode_kernel, dim3(NEDU), dim3(256), 0, stream,
                     edu_words, edu_poses, word_emb, pos_emb, bu, bb, bt, ws);
  hipLaunchKernelGGL(proj_kernel, dim3(16, 8), dim3(256), 0, stream, Wp, bp, ws);

  void* args[] = { (void*)&transes, (void*)&nT, (void*)&Wih, (void*)&Whh, (void*)&bih,
                   (void*)&bhh, (void*)&Wc, (void*)&bc, (void*)&Wsc, (void*)&ws };
  hipLaunchCooperativeKernel((const void*)parse_kernel, dim3(NWG), dim3(64), args, 0, stream);

  hipLaunchKernelGGL(loss_kernel, dim3(1), dim3(256), 0, stream, transes, nT, bsc, ws, out);
}